// Round 8
// baseline (446.017 us; speedup 1.0000x reference)
//
#include <hip/hip_runtime.h>
#include <cstdint>

// scan geometry
#define SL 2048
#define SE 2048
#define SB 2
#define SN 16
#define SC 64
#define ST 32

enum { EP_SPLIT_SILU = 1, EP_PARTIAL = 4, EP_BF16 = 5, EP_FUSED34 = 6 };

typedef __attribute__((ext_vector_type(8))) short bf16x8;
typedef __attribute__((ext_vector_type(4))) float f32x4;

__device__ __forceinline__ float silu_f(float x) { return x / (1.f + __expf(-x)); }
__device__ __forceinline__ float softplus_f(float x) {
    return (x > 20.f) ? x : log1pf(__expf(x));
}
__device__ __forceinline__ ushort f2bf(float f) {
    union { float f; unsigned u; } a; a.f = f;
    unsigned r = a.u + 0x7fff + ((a.u >> 16) & 1);
    return (ushort)(r >> 16);
}
__device__ __forceinline__ float bf2f(ushort u) {
    union { float f; unsigned u; } a; a.u = ((unsigned)u) << 16;
    return a.f;
}
__device__ __forceinline__ void gload16(const void* g, void* l) {
    __builtin_amdgcn_global_load_lds(
        (const __attribute__((address_space(1))) unsigned int*)g,
        (__attribute__((address_space(3))) unsigned int*)l, 16, 0, 0);
}

// ---- 128x128 bf16 MFMA GEMM, BK=64, dbuf LDS, 2-phase pipeline.
// C(MxN) = A(MxK) * Bt(NxK)^T. blockIdx.z = split-K slice of size KS.
// B rows clamped to N-1 (tiles overhanging N); stores masked per-mode.
template <int MODE>
__global__ __launch_bounds__(256, 2) void hgemm2(
    const ushort* __restrict__ A, const ushort* __restrict__ Bt,
    float* __restrict__ C, const float* __restrict__ bias,
    float* __restrict__ out2, ushort* __restrict__ outu,
    int M, int N, int K, int Esplit, int KS)
{
    __shared__ ushort As[2][128 * 64];
    __shared__ ushort Bs[2][128 * 64];
    const int tid = threadIdx.x;
    const int w = tid >> 6, l = tid & 63;
    const int wr = w >> 1, wc = w & 1;
    const int m0 = blockIdx.y * 128, n0 = blockIdx.x * 128;
    const int z = blockIdx.z;
    const int kbeg = z * KS;
    const int nt = KS / 64;
    const int srow = l >> 3, scol = (l & 7) * 8;

    f32x4 acc[4][4];
#pragma unroll
    for (int m = 0; m < 4; m++)
#pragma unroll
        for (int n = 0; n < 4; n++) acc[m][n] = (f32x4)(0.f);

    auto stage = [&](int buf, int t) {
        const int k0 = kbeg + t * 64;
#pragma unroll
        for (int r = 0; r < 4; r++) {
            const int row = r * 32 + w * 8 + srow;
            int brow = n0 + row; if (brow > N - 1) brow = N - 1;
            gload16(A + (size_t)(m0 + row) * K + k0 + scol,
                    &As[buf][r * 2048 + w * 512]);
            gload16(Bt + (size_t)brow * K + k0 + scol,
                    &Bs[buf][r * 2048 + w * 512]);
        }
    };

    stage(0, 0);
    __syncthreads();

    int cur = 0;
    const int fr = l & 15, kc = (l >> 4) * 8;
    for (int t = 0; t < nt; t++) {
        if (t + 1 < nt) stage(cur ^ 1, t + 1);
#pragma unroll
        for (int kk = 0; kk < 64; kk += 32) {
            bf16x8 af[4], bfr[4];
#pragma unroll
            for (int m = 0; m < 4; m++)
                af[m] = *(const bf16x8*)&As[cur][(wr * 64 + m * 16 + fr) * 64 + kk + kc];
#pragma unroll
            for (int n = 0; n < 4; n++)
                bfr[n] = *(const bf16x8*)&Bs[cur][(wc * 64 + n * 16 + fr) * 64 + kk + kc];
#pragma unroll
            for (int m = 0; m < 4; m++)
#pragma unroll
                for (int n = 0; n < 4; n++)
                    acc[m][n] = __builtin_amdgcn_mfma_f32_16x16x32_bf16(
                        af[m], bfr[n], acc[m][n], 0, 0, 0);
        }
        __syncthreads();
        cur ^= 1;
    }

    const int cr = (l >> 4) * 4, cc = l & 15;
    float* pbase = C + (size_t)z * M * N;   // EP_PARTIAL
#pragma unroll
    for (int m = 0; m < 4; m++) {
#pragma unroll
        for (int j = 0; j < 4; j++) {
            const int row = m0 + wr * 64 + m * 16 + cr + j;
#pragma unroll
            for (int n = 0; n < 4; n++) {
                const int col = n0 + wc * 64 + n * 16 + cc;
                float v = acc[m][n][j];
                if (MODE == EP_SPLIT_SILU) {
                    v += bias[col];
                    if (col < Esplit)
                        C[(size_t)row * Esplit + col] = v;
                    else
                        out2[(size_t)row * Esplit + (col - Esplit)] = silu_f(v);
                } else if (MODE == EP_FUSED34) {
                    // cols < Esplit: delta = softplus(v + dt_bias); next 32: B/C
                    if (col < Esplit)
                        C[(size_t)row * Esplit + col] = softplus_f(v + bias[col]);
                    else if (col < N)
                        out2[(size_t)row * 32 + (col - Esplit)] = v;
                } else if (MODE == EP_BF16) {
                    outu[(size_t)row * N + col] = f2bf(v);
                } else {  // EP_PARTIAL
                    if (col < N) pbase[(size_t)row * N + col] = v;
                }
            }
        }
    }
}

// Reduce GEMM6 split-K(Z) partials + bias -> out fp32 (float4).
__global__ __launch_bounds__(256) void reduce6(
    const float* __restrict__ Pp, const float* __restrict__ bias,
    float* __restrict__ out, int M, int N, int Z)
{
    const size_t g = (size_t)blockIdx.x * 256 + threadIdx.x;
    const size_t tot4 = (size_t)M * N / 4;
    if (g >= tot4) return;
    const int n4 = N / 4;
    float4 s = ((const float4*)bias)[g % n4];
    for (int z = 0; z < Z; z++) {
        float4 p = ((const float4*)Pp)[z * tot4 + g];
        s.x += p.x; s.y += p.y; s.z += p.z; s.w += p.w;
    }
    ((float4*)out)[g] = s;
}

// fp32 -> bf16 copy (vectorized)
__global__ __launch_bounds__(256) void f2bf_vec(
    const float* __restrict__ in, ushort* __restrict__ out, size_t n4)
{
    for (size_t i = (size_t)blockIdx.x * 256 + threadIdx.x; i < n4;
         i += (size_t)gridDim.x * 256) {
        float4 v = ((const float4*)in)[i];
        ushort4 o;
        o.x = f2bf(v.x); o.y = f2bf(v.y); o.z = f2bf(v.z); o.w = f2bf(v.w);
        ((ushort4*)out)[i] = o;
    }
}

// W (R x Ccols) fp32 -> Wt (Ccols x R) bf16, tiled transpose
__global__ __launch_bounds__(256) void f2bf_transpose(
    const float* __restrict__ W, ushort* __restrict__ Wt, int R, int Ccols)
{
    __shared__ float tile[32][33];
    const int bc = blockIdx.x * 32, br = blockIdx.y * 32;
    const int tx = threadIdx.x & 31, ty = threadIdx.x >> 5;
    for (int i = ty; i < 32; i += 8)
        tile[i][tx] = W[(size_t)(br + i) * Ccols + bc + tx];
    __syncthreads();
    for (int i = ty; i < 32; i += 8)
        Wt[(size_t)(bc + i) * R + br + tx] = f2bf(tile[tx][i]);
}

// x_proj_w (2048 x 160) cols 0..127 -> dense bf16 (2048 x 128)
__global__ __launch_bounds__(256) void cast_xpw128(
    const float* __restrict__ W, ushort* __restrict__ out)
{
    const int idx = blockIdx.x * 256 + threadIdx.x;   // over 2048*32
    if (idx >= 2048 * 32) return;
    const int row = idx >> 5;
    const int c4 = (idx & 31) * 4;
    const float4 v = *(const float4*)&W[(size_t)row * 160 + c4];
    ushort4 o;
    o.x = f2bf(v.x); o.y = f2bf(v.y); o.z = f2bf(v.z); o.w = f2bf(v.w);
    *(ushort4*)&out[(size_t)row * 128 + c4] = o;
}

// x_proj_w cols 128..159 transposed -> Wt rows (32 x 2048) bf16
__global__ __launch_bounds__(256) void bc_weight_t(
    const float* __restrict__ W, ushort* __restrict__ Wt)
{
    __shared__ float tile[32][33];
    const int br = blockIdx.y * 32;  // k-block
    const int tx = threadIdx.x & 31, ty = threadIdx.x >> 5;
    for (int i = ty; i < 32; i += 8)
        tile[i][tx] = W[(size_t)(br + i) * 160 + 128 + tx];
    __syncthreads();
    for (int i = ty; i < 32; i += 8)
        Wt[(size_t)i * 2048 + br + tx] = f2bf(tile[tx][i]);
}

// Depthwise causal conv (K=4) + bias + SiLU; 4 ch/thread; bf16 output only.
__global__ __launch_bounds__(256) void conv_silu4(
    const float* __restrict__ xin, const float* __restrict__ w,
    const float* __restrict__ cb, ushort* __restrict__ xobf,
    int Ln, int En, size_t total4)
{
    const int Eq = En >> 2;
    for (size_t idx = (size_t)blockIdx.x * 256 + threadIdx.x; idx < total4;
         idx += (size_t)gridDim.x * 256) {
        const int e4 = (int)(idx % Eq);
        const size_t row = idx / Eq;
        const int l = (int)(row % Ln);
        float4 acc = ((const float4*)cb)[e4];
        const float4 w0 = ((const float4*)w)[e4 * 4 + 0];
        const float4 w1 = ((const float4*)w)[e4 * 4 + 1];
        const float4 w2 = ((const float4*)w)[e4 * 4 + 2];
        const float4 w3 = ((const float4*)w)[e4 * 4 + 3];
        const float wt0[4] = {w0.x, w0.y, w0.z, w0.w};
        const float wt1[4] = {w1.x, w1.y, w1.z, w1.w};
        const float wt2[4] = {w2.x, w2.y, w2.z, w2.w};
        const float wt3[4] = {w3.x, w3.y, w3.z, w3.w};
#pragma unroll
        for (int k = 0; k < 4; k++) {
            if (l - 3 + k >= 0) {
                float4 xv = ((const float4*)xin)[(row - 3 + k) * Eq + e4];
                acc.x = fmaf(wt0[k], xv.x, acc.x);
                acc.y = fmaf(wt1[k], xv.y, acc.y);
                acc.z = fmaf(wt2[k], xv.z, acc.z);
                acc.w = fmaf(wt3[k], xv.w, acc.w);
            }
        }
        ushort4 o;
        o.x = f2bf(silu_f(acc.x)); o.y = f2bf(silu_f(acc.y));
        o.z = f2bf(silu_f(acc.z)); o.w = f2bf(silu_f(acc.w));
        ((ushort4*)xobf)[idx] = o;
    }
}

// ---- Chunked parallel selective scan (u in bf16, B/C from compact buffer) ----
__global__ __launch_bounds__(256) void scan_pass1(
    const float* __restrict__ delta, const ushort* __restrict__ u,
    const float* __restrict__ BC, const float* __restrict__ A_log,
    float* __restrict__ Pbuf, float* __restrict__ Sbuf)
{
    __shared__ float sB[ST * SN];
    const int tid = threadIdx.x;
    const int eb = blockIdx.x & 7;
    const int c  = (blockIdx.x >> 3) & (SC - 1);
    const int b  = blockIdx.x >> 9;
    const int e  = eb * 256 + tid;
    const size_t row0 = (size_t)b * SL + c * ST;

    for (int i = tid; i < ST * SN; i += 256)
        sB[i] = BC[(row0 + (i >> 4)) * 32 + (i & 15)];
    __syncthreads();

    float An[SN], h[SN];
    {
        const float4* Ap = (const float4*)(A_log + (size_t)e * SN);
#pragma unroll
        for (int q = 0; q < 4; q++) {
            float4 v = Ap[q];
            An[q * 4 + 0] = -expf(v.x);
            An[q * 4 + 1] = -expf(v.y);
            An[q * 4 + 2] = -expf(v.z);
            An[q * 4 + 3] = -expf(v.w);
        }
    }
#pragma unroll
    for (int n = 0; n < SN; n++) h[n] = 0.f;

    float dsum = 0.f;
    size_t idx = row0 * SE + e;
    float d = delta[idx], uu = bf2f(u[idx]);
    for (int tl = 0; tl < ST; tl++) {
        float dn = 0.f, un = 0.f;
        if (tl + 1 < ST) { dn = delta[idx + SE]; un = bf2f(u[idx + SE]); }
        const float du = d * uu;
        dsum += d;
#pragma unroll
        for (int n = 0; n < SN; n++) {
            const float dA = __expf(d * An[n]);
            h[n] = fmaf(dA, h[n], du * sB[tl * SN + n]);
        }
        d = dn; uu = un; idx += SE;
    }

    const size_t ob = ((((size_t)c * SB) + b) * SE + e) * SN;
#pragma unroll
    for (int q = 0; q < 4; q++) {
        float4 pv, sv;
        pv.x = __expf(An[q * 4 + 0] * dsum); sv.x = h[q * 4 + 0];
        pv.y = __expf(An[q * 4 + 1] * dsum); sv.y = h[q * 4 + 1];
        pv.z = __expf(An[q * 4 + 2] * dsum); sv.z = h[q * 4 + 2];
        pv.w = __expf(An[q * 4 + 3] * dsum); sv.w = h[q * 4 + 3];
        *(float4*)(Pbuf + ob + q * 4) = pv;
        *(float4*)(Sbuf + ob + q * 4) = sv;
    }
}

__global__ __launch_bounds__(256) void scan_pass2(
    const float* __restrict__ Pbuf, const float* __restrict__ Sbuf,
    float* __restrict__ hinit)
{
    const size_t g = (size_t)blockIdx.x * 256 + threadIdx.x;
    const size_t stride = (size_t)SB * SE * SN;
    float h = 0.f;
    float P = Pbuf[g], S = Sbuf[g];
    for (int c = 0; c < SC; c++) {
        float Pn = 0.f, Sn = 0.f;
        if (c + 1 < SC) {
            Pn = Pbuf[(c + 1) * stride + g];
            Sn = Sbuf[(c + 1) * stride + g];
        }
        hinit[c * stride + g] = h;
        h = fmaf(P, h, S);
        P = Pn; S = Sn;
    }
}

__global__ __launch_bounds__(256) void scan_pass3(
    const float* __restrict__ delta, const ushort* __restrict__ u,
    const float* __restrict__ BC, const float* __restrict__ A_log,
    const float* __restrict__ Dp, const float* __restrict__ xr,
    const float* __restrict__ hinit, ushort* __restrict__ yg)
{
    __shared__ float sB[ST * SN];
    __shared__ float sC[ST * SN];
    const int tid = threadIdx.x;
    const int eb = blockIdx.x & 7;
    const int c  = (blockIdx.x >> 3) & (SC - 1);
    const int b  = blockIdx.x >> 9;
    const int e  = eb * 256 + tid;
    const size_t row0 = (size_t)b * SL + c * ST;

    for (int i = tid; i < ST * SN; i += 256) {
        sB[i] = BC[(row0 + (i >> 4)) * 32 + (i & 15)];
        sC[i] = BC[(row0 + (i >> 4)) * 32 + 16 + (i & 15)];
    }
    __syncthreads();

    float An[SN], h[SN];
    {
        const float4* Ap = (const float4*)(A_log + (size_t)e * SN);
#pragma unroll
        for (int q = 0; q < 4; q++) {
            float4 v = Ap[q];
            An[q * 4 + 0] = -expf(v.x);
            An[q * 4 + 1] = -expf(v.y);
            An[q * 4 + 2] = -expf(v.z);
            An[q * 4 + 3] = -expf(v.w);
        }
    }
    {
        const size_t ib = ((((size_t)c * SB) + b) * SE + e) * SN;
#pragma unroll
        for (int q = 0; q < 4; q++) {
            float4 v = *(const float4*)(hinit + ib + q * 4);
            h[q * 4 + 0] = v.x; h[q * 4 + 1] = v.y;
            h[q * 4 + 2] = v.z; h[q * 4 + 3] = v.w;
        }
    }
    const float De = Dp[e];

    size_t idx = row0 * SE + e;
    float d = delta[idx], uu = bf2f(u[idx]), g = xr[idx];
    for (int tl = 0; tl < ST; tl++) {
        float dn = 0.f, un = 0.f, gn = 0.f;
        if (tl + 1 < ST) {
            dn = delta[idx + SE]; un = bf2f(u[idx + SE]); gn = xr[idx + SE];
        }
        const float du = d * uu;
        float y = 0.f;
#pragma unroll
        for (int n = 0; n < SN; n++) {
            const float dA = __expf(d * An[n]);
            h[n] = fmaf(dA, h[n], du * sB[tl * SN + n]);
            y = fmaf(h[n], sC[tl * SN + n], y);
        }
        yg[idx] = f2bf((y + uu * De) * g);
        d = dn; uu = un; g = gn; idx += SE;
    }
}

extern "C" void kernel_launch(void* const* d_in, const int* in_sizes, int n_in,
                              void* d_out, int out_size, void* d_ws, size_t ws_size,
                              hipStream_t stream)
{
    const int Bc = 2, Lc = 2048, Hc = 1024, Ec = 2048;
    const int M = Bc * Lc;      // 4096
    const int NF = 2080;        // fused GEMM34 output cols (2048 delta + 32 B/C)
    const int SK6 = 2;          // GEMM6 split-K

    const float* x        = (const float*)d_in[0];
    const float* W_in     = (const float*)d_in[1];
    const float* b_in     = (const float*)d_in[2];
    const float* conv_w   = (const float*)d_in[3];
    const float* conv_b   = (const float*)d_in[4];
    const float* x_proj_w = (const float*)d_in[5];
    const float* dt_proj_w= (const float*)d_in[6];
    const float* dt_bias  = (const float*)d_in[7];
    const float* A_log    = (const float*)d_in[8];
    const float* D_param  = (const float*)d_in[9];
    const float* W_out    = (const float*)d_in[10];
    const float* b_out    = (const float*)d_in[11];
    float* out = (float*)d_out;

    float* ws = (float*)d_ws;
    const size_t ME = (size_t)M * Ec;            // 8,388,608 floats
    const size_t PS = (size_t)SB * SE * SC * SN; // 4,194,304 floats

    // region map (floats):
    float* xc_raw = ws;                    // R0 (ME): GEMM1 z-out -> Pbuf,Sbuf -> ygbf
    float* xr     = xc_raw + ME;           // R1 (ME): xr gate -> Pp6 after pass3
    float* r2     = xr + ME;               // R2 (ME/2): W_in_t early -> xc_bf
    float* delta  = r2 + ME / 2;           // R3 (ME): xbf early -> delta -> W_out_t
    float* hinit  = delta + ME;            // R4 (PS)
    ushort* Wbig  = (ushort*)(hinit + PS); // R5: 2176*2048 ushorts
    float* BC     = (float*)(Wbig + (size_t)2176 * 2048);  // R6: M*32 floats
    ushort* xpw128= (ushort*)(BC + (size_t)M * 32);        // R7a: 2048*128 us
    ushort* dtw_t = xpw128 + (size_t)2048 * 128;           // R7b: 2048*128 us

    ushort* xbf    = (ushort*)delta;       // dead after GEMM1
    ushort* W_in_t = (ushort*)r2;          // dead after GEMM1
    ushort* xc_bf  = (ushort*)r2;          // conv out; read by GEMM34 + scans (u)
    float*  Pbuf   = xc_raw;
    float*  Sbuf   = xc_raw + PS;
    ushort* ygbf   = (ushort*)xc_raw;      // pass3 out (P/S dead)
    ushort* W_out_t= (ushort*)delta;       // after pass3 (delta dead)
    float*  Pp6    = xr;                   // SK6*M*1024 = 8.39M floats (xr dead)

    // 0) conversions / weight preps
    f2bf_vec<<<1024, 256, 0, stream>>>(x, xbf, (size_t)M * Hc / 4);
    f2bf_transpose<<<dim3(2 * Ec / 32, Hc / 32), 256, 0, stream>>>(
        W_in, W_in_t, Hc, 2 * Ec);
    cast_xpw128<<<256, 256, 0, stream>>>(x_proj_w, xpw128);
    f2bf_transpose<<<dim3(Ec / 32, 128 / 32), 256, 0, stream>>>(
        dt_proj_w, dtw_t, 128, Ec);
    bc_weight_t<<<dim3(1, Ec / 32), 256, 0, stream>>>(
        x_proj_w, Wbig + (size_t)2048 * 2048);

    // 0b) W_comb^T = dt_proj_w^T @ x_proj_w[:,:128]^T -> Wbig rows 0..2047 (bf16)
    hgemm2<EP_BF16><<<dim3(16, 16, 1), 256, 0, stream>>>(
        dtw_t, xpw128, nullptr, nullptr, nullptr, Wbig, 2048, 2048, 128, 0, 128);

    // 1) z = x @ W_in + b_in ; split -> xc_raw (fp32), silu -> xr (fp32)
    hgemm2<EP_SPLIT_SILU><<<dim3(2 * Ec / 128, M / 128, 1), 256, 0, stream>>>(
        xbf, W_in_t, xc_raw, b_in, xr, nullptr, M, 2 * Ec, Hc, Ec, Hc);

    // 2) depthwise causal conv + bias + silu -> xc_bf (bf16 only)
    conv_silu4<<<2048, 256, 0, stream>>>(
        xc_raw, conv_w, conv_b, xc_bf, Lc, Ec, ME / 4);

    // 3+4 fused) [delta | B/C] = xc @ [W_comb | x_proj_w[:,128:]]
    //   cols<2048: softplus(v+dt_bias) -> delta; cols 2048..2079 -> BC
    hgemm2<EP_FUSED34><<<dim3((NF + 127) / 128, M / 128, 1), 256, 0, stream>>>(
        xc_bf, Wbig, delta, dt_bias, BC, nullptr, M, NF, Ec, Ec, Ec);

    // 5) chunked parallel scan; pass3 emits bf16 yg
    scan_pass1<<<SB * SC * (SE / 256), 256, 0, stream>>>(
        delta, xc_bf, BC, A_log, Pbuf, Sbuf);
    scan_pass2<<<(SB * SE * SN) / 256, 256, 0, stream>>>(Pbuf, Sbuf, hinit);
    scan_pass3<<<SB * SC * (SE / 256), 256, 0, stream>>>(
        delta, xc_bf, BC, A_log, D_param, xr, hinit, ygbf);

    // 5b) W_out (E x H) -> bf16 (H x E)  (delta dead now)
    f2bf_transpose<<<dim3(Hc / 32, Ec / 32), 256, 0, stream>>>(
        W_out, W_out_t, Ec, Hc);

    // 6) out = yg @ W_out : split-K=2 partials + bias reduce
    hgemm2<EP_PARTIAL><<<dim3(Hc / 128, M / 128, SK6), 256, 0, stream>>>(
        ygbf, W_out_t, Pp6, nullptr, nullptr, nullptr, M, Hc, Ec, 0, Ec / SK6);
    reduce6<<<(int)((size_t)M * Hc / 4 + 255) / 256, 256, 0, stream>>>(
        Pp6, b_out, out, M, Hc, SK6);
}

// Round 9
// 360.877 us; speedup vs baseline: 1.2359x; 1.2359x over previous
//
#include <hip/hip_runtime.h>
#include <cstdint>

// scan geometry
#define SL 2048
#define SE 2048
#define SB 2
#define SN 16
#define SC 64
#define ST 32

enum { EP_SPLIT_SILU = 1, EP_SOFTPLUS = 2, EP_BIAS = 3, EP_PARTIAL = 4 };

typedef __attribute__((ext_vector_type(8))) short bf16x8;
typedef __attribute__((ext_vector_type(4))) float f32x4;

__device__ __forceinline__ float silu_f(float x) { return x / (1.f + __expf(-x)); }
__device__ __forceinline__ float softplus_f(float x) {
    return (x > 20.f) ? x : log1pf(__expf(x));
}
__device__ __forceinline__ ushort f2bf(float f) {
    union { float f; unsigned u; } a; a.f = f;
    unsigned r = a.u + 0x7fff + ((a.u >> 16) & 1);
    return (ushort)(r >> 16);
}
__device__ __forceinline__ void gload16(const void* g, void* l) {
    __builtin_amdgcn_global_load_lds(
        (const __attribute__((address_space(1))) unsigned int*)g,
        (__attribute__((address_space(3))) unsigned int*)l, 16, 0, 0);
}

// ---- shared 128x128 bf16 MFMA GEMM body, BK=64, dbuf LDS, 2-phase ----
// C(MxN) = A(MxK) * Bt(NxK)^T. z = split-K slice of size KS.
template <int MODE>
__device__ __forceinline__ void gemm_body(
    const ushort* __restrict__ A, const ushort* __restrict__ Bt,
    float* __restrict__ C, const float* __restrict__ bias,
    float* __restrict__ out2, int M, int N, int K, int Esplit, int KS)
{
    __shared__ ushort As[2][128 * 64];
    __shared__ ushort Bs[2][128 * 64];
    const int tid = threadIdx.x;
    const int w = tid >> 6, l = tid & 63;
    const int wr = w >> 1, wc = w & 1;
    const int m0 = blockIdx.y * 128, n0 = blockIdx.x * 128;
    const int z = blockIdx.z;
    const int kbeg = z * KS;
    const int nt = KS / 64;
    const int srow = l >> 3, scol = (l & 7) * 8;

    f32x4 acc[4][4];
#pragma unroll
    for (int m = 0; m < 4; m++)
#pragma unroll
        for (int n = 0; n < 4; n++) acc[m][n] = (f32x4)(0.f);

    auto stage = [&](int buf, int t) {
        const int k0 = kbeg + t * 64;
#pragma unroll
        for (int r = 0; r < 4; r++) {
            const int row = r * 32 + w * 8 + srow;
            int brow = n0 + row; if (brow > N - 1) brow = N - 1;
            gload16(A + (size_t)(m0 + row) * K + k0 + scol,
                    &As[buf][r * 2048 + w * 512]);
            gload16(Bt + (size_t)brow * K + k0 + scol,
                    &Bs[buf][r * 2048 + w * 512]);
        }
    };

    stage(0, 0);
    __syncthreads();

    int cur = 0;
    const int fr = l & 15, kc = (l >> 4) * 8;
    for (int t = 0; t < nt; t++) {
        if (t + 1 < nt) stage(cur ^ 1, t + 1);
#pragma unroll
        for (int kk = 0; kk < 64; kk += 32) {
            bf16x8 af[4], bfr[4];
#pragma unroll
            for (int m = 0; m < 4; m++)
                af[m] = *(const bf16x8*)&As[cur][(wr * 64 + m * 16 + fr) * 64 + kk + kc];
#pragma unroll
            for (int n = 0; n < 4; n++)
                bfr[n] = *(const bf16x8*)&Bs[cur][(wc * 64 + n * 16 + fr) * 64 + kk + kc];
#pragma unroll
            for (int m = 0; m < 4; m++)
#pragma unroll
                for (int n = 0; n < 4; n++)
                    acc[m][n] = __builtin_amdgcn_mfma_f32_16x16x32_bf16(
                        af[m], bfr[n], acc[m][n], 0, 0, 0);
        }
        __syncthreads();
        cur ^= 1;
    }

    const int cr = (l >> 4) * 4, cc = l & 15;
    float* pbase = C + (size_t)z * M * N;
#pragma unroll
    for (int m = 0; m < 4; m++) {
#pragma unroll
        for (int j = 0; j < 4; j++) {
            const int row = m0 + wr * 64 + m * 16 + cr + j;
#pragma unroll
            for (int n = 0; n < 4; n++) {
                const int col = n0 + wc * 64 + n * 16 + cc;
                float v = acc[m][n][j];
                if (MODE == EP_SPLIT_SILU) {
                    v += bias[col];
                    if (col < Esplit)
                        C[(size_t)row * Esplit + col] = v;
                    else
                        out2[(size_t)row * Esplit + (col - Esplit)] = silu_f(v);
                } else if (MODE == EP_BIAS) {
                    C[(size_t)row * N + col] = v + bias[col];
                } else {  // EP_PARTIAL
                    if (col < N) pbase[(size_t)row * N + col] = v;
                }
            }
        }
    }
}

// Distinct names for unambiguous profiling:
__global__ __launch_bounds__(256, 2) void g1_gemm(
    const ushort* __restrict__ A, const ushort* __restrict__ Bt,
    float* __restrict__ C, const float* __restrict__ bias,
    float* __restrict__ out2, int M, int N, int K, int Esplit, int KS)
{ gemm_body<EP_SPLIT_SILU>(A, Bt, C, bias, out2, M, N, K, Esplit, KS); }

__global__ __launch_bounds__(256, 2) void g3_gemm(
    const ushort* __restrict__ A, const ushort* __restrict__ Bt,
    float* __restrict__ C, int M, int N, int K, int KS)
{ gemm_body<EP_PARTIAL>(A, Bt, C, nullptr, nullptr, M, N, K, 0, KS); }

__global__ __launch_bounds__(256, 2) void g6_gemm(
    const ushort* __restrict__ A, const ushort* __restrict__ Bt,
    float* __restrict__ C, int M, int N, int K, int KS)
{ gemm_body<EP_PARTIAL>(A, Bt, C, nullptr, nullptr, M, N, K, 0, KS); }

// ---- GEMM4 dedicated: K=128, single-buffer 32KB, max co-residency ----
__global__ __launch_bounds__(256) void g4_gemm(
    const ushort* __restrict__ A, const ushort* __restrict__ Bt,
    float* __restrict__ C, const float* __restrict__ bias, int M, int N)
{
    __shared__ ushort As[128 * 64];
    __shared__ ushort Bs[128 * 64];
    const int tid = threadIdx.x;
    const int w = tid >> 6, l = tid & 63;
    const int wr = w >> 1, wc = w & 1;
    const int m0 = blockIdx.y * 128, n0 = blockIdx.x * 128;
    const int srow = l >> 3, scol = (l & 7) * 8;
    const int K = 128;

    f32x4 acc[4][4];
#pragma unroll
    for (int m = 0; m < 4; m++)
#pragma unroll
        for (int n = 0; n < 4; n++) acc[m][n] = (f32x4)(0.f);

    const int fr = l & 15, kc = (l >> 4) * 8;
#pragma unroll
    for (int t = 0; t < 2; t++) {
        const int k0 = t * 64;
#pragma unroll
        for (int r = 0; r < 4; r++) {
            const int row = r * 32 + w * 8 + srow;
            gload16(A + (size_t)(m0 + row) * K + k0 + scol, &As[r * 2048 + w * 512]);
            gload16(Bt + (size_t)(n0 + row) * K + k0 + scol, &Bs[r * 2048 + w * 512]);
        }
        __syncthreads();
#pragma unroll
        for (int kk = 0; kk < 64; kk += 32) {
            bf16x8 af[4], bfr[4];
#pragma unroll
            for (int m = 0; m < 4; m++)
                af[m] = *(const bf16x8*)&As[(wr * 64 + m * 16 + fr) * 64 + kk + kc];
#pragma unroll
            for (int n = 0; n < 4; n++)
                bfr[n] = *(const bf16x8*)&Bs[(wc * 64 + n * 16 + fr) * 64 + kk + kc];
#pragma unroll
            for (int m = 0; m < 4; m++)
#pragma unroll
                for (int n = 0; n < 4; n++)
                    acc[m][n] = __builtin_amdgcn_mfma_f32_16x16x32_bf16(
                        af[m], bfr[n], acc[m][n], 0, 0, 0);
        }
        __syncthreads();
    }

    const int cr = (l >> 4) * 4, cc = l & 15;
#pragma unroll
    for (int m = 0; m < 4; m++) {
#pragma unroll
        for (int j = 0; j < 4; j++) {
            const int row = m0 + wr * 64 + m * 16 + cr + j;
#pragma unroll
            for (int n = 0; n < 4; n++) {
                const int col = n0 + wc * 64 + n * 16 + cc;
                C[(size_t)row * N + col] = softplus_f(acc[m][n][j] + bias[col]);
            }
        }
    }
}

// Reduce split-K partials -> proj fp32; also emit dt columns (<128) as bf16.
__global__ __launch_bounds__(256) void gemm3_reduce(
    const float* __restrict__ Pp, float* __restrict__ proj,
    ushort* __restrict__ dtbf, int M, int N, int Z)
{
    const size_t g = (size_t)blockIdx.x * 256 + threadIdx.x;
    const size_t tot = (size_t)M * N;
    if (g >= tot) return;
    float s = 0.f;
    for (int z = 0; z < Z; z++) s += Pp[(size_t)z * tot + g];
    proj[g] = s;
    const int col = (int)(g % N);
    if (col < 128) {
        const size_t row = g / N;
        dtbf[row * 128 + col] = f2bf(s);
    }
}

// Reduce GEMM6 split-K(Z) partials + bias -> out fp32 (float4).
__global__ __launch_bounds__(256) void reduce6(
    const float* __restrict__ Pp, const float* __restrict__ bias,
    float* __restrict__ out, int M, int N, int Z)
{
    const size_t g = (size_t)blockIdx.x * 256 + threadIdx.x;
    const size_t tot4 = (size_t)M * N / 4;
    if (g >= tot4) return;
    const int n4 = N / 4;
    float4 s = ((const float4*)bias)[g % n4];
    for (int z = 0; z < Z; z++) {
        float4 p = ((const float4*)Pp)[z * tot4 + g];
        s.x += p.x; s.y += p.y; s.z += p.z; s.w += p.w;
    }
    ((float4*)out)[g] = s;
}

// fp32 -> bf16 copy (vectorized)
__global__ __launch_bounds__(256) void f2bf_vec(
    const float* __restrict__ in, ushort* __restrict__ out, size_t n4)
{
    for (size_t i = (size_t)blockIdx.x * 256 + threadIdx.x; i < n4;
         i += (size_t)gridDim.x * 256) {
        float4 v = ((const float4*)in)[i];
        ushort4 o;
        o.x = f2bf(v.x); o.y = f2bf(v.y); o.z = f2bf(v.z); o.w = f2bf(v.w);
        ((ushort4*)out)[i] = o;
    }
}

// W (R x Ccols) fp32 -> Wt (Ccols x R) bf16, tiled transpose
__global__ __launch_bounds__(256) void f2bf_transpose(
    const float* __restrict__ W, ushort* __restrict__ Wt, int R, int Ccols)
{
    __shared__ float tile[32][33];
    const int bc = blockIdx.x * 32, br = blockIdx.y * 32;
    const int tx = threadIdx.x & 31, ty = threadIdx.x >> 5;
    for (int i = ty; i < 32; i += 8)
        tile[i][tx] = W[(size_t)(br + i) * Ccols + bc + tx];
    __syncthreads();
    for (int i = ty; i < 32; i += 8)
        Wt[(size_t)(bc + i) * R + br + tx] = f2bf(tile[tx][i]);
}

// Depthwise causal conv (K=4) + bias + SiLU; 4 ch/thread; fp32 + bf16 outputs.
__global__ __launch_bounds__(256) void conv_silu4(
    const float* __restrict__ xin, const float* __restrict__ w,
    const float* __restrict__ cb, float* __restrict__ xo,
    ushort* __restrict__ xobf, int Ln, int En, size_t total4)
{
    const int Eq = En >> 2;
    for (size_t idx = (size_t)blockIdx.x * 256 + threadIdx.x; idx < total4;
         idx += (size_t)gridDim.x * 256) {
        const int e4 = (int)(idx % Eq);
        const size_t row = idx / Eq;
        const int l = (int)(row % Ln);
        float4 acc = ((const float4*)cb)[e4];
        const float4 w0 = ((const float4*)w)[e4 * 4 + 0];
        const float4 w1 = ((const float4*)w)[e4 * 4 + 1];
        const float4 w2 = ((const float4*)w)[e4 * 4 + 2];
        const float4 w3 = ((const float4*)w)[e4 * 4 + 3];
        const float wt0[4] = {w0.x, w0.y, w0.z, w0.w};
        const float wt1[4] = {w1.x, w1.y, w1.z, w1.w};
        const float wt2[4] = {w2.x, w2.y, w2.z, w2.w};
        const float wt3[4] = {w3.x, w3.y, w3.z, w3.w};
#pragma unroll
        for (int k = 0; k < 4; k++) {
            if (l - 3 + k >= 0) {
                float4 xv = ((const float4*)xin)[(row - 3 + k) * Eq + e4];
                acc.x = fmaf(wt0[k], xv.x, acc.x);
                acc.y = fmaf(wt1[k], xv.y, acc.y);
                acc.z = fmaf(wt2[k], xv.z, acc.z);
                acc.w = fmaf(wt3[k], xv.w, acc.w);
            }
        }
        float4 v;
        v.x = silu_f(acc.x); v.y = silu_f(acc.y);
        v.z = silu_f(acc.z); v.w = silu_f(acc.w);
        ((float4*)xo)[idx] = v;
        ushort4 o;
        o.x = f2bf(v.x); o.y = f2bf(v.y); o.z = f2bf(v.z); o.w = f2bf(v.w);
        ((ushort4*)xobf)[idx] = o;
    }
}

// ---- Chunked parallel selective scan ----
__global__ __launch_bounds__(256) void scan_pass1(
    const float* __restrict__ delta, const float* __restrict__ u,
    const float* __restrict__ proj, const float* __restrict__ A_log,
    float* __restrict__ Pbuf, float* __restrict__ Sbuf)
{
    __shared__ float sB[ST * SN];
    const int tid = threadIdx.x;
    const int eb = blockIdx.x & 7;
    const int c  = (blockIdx.x >> 3) & (SC - 1);
    const int b  = blockIdx.x >> 9;
    const int e  = eb * 256 + tid;
    const size_t row0 = (size_t)b * SL + c * ST;

    for (int i = tid; i < ST * SN; i += 256) {
        const int tl = i >> 4, n = i & 15;
        sB[i] = proj[(row0 + tl) * 160 + 128 + n];
    }
    __syncthreads();

    float An[SN], h[SN];
    {
        const float4* Ap = (const float4*)(A_log + (size_t)e * SN);
#pragma unroll
        for (int q = 0; q < 4; q++) {
            float4 v = Ap[q];
            An[q * 4 + 0] = -expf(v.x);
            An[q * 4 + 1] = -expf(v.y);
            An[q * 4 + 2] = -expf(v.z);
            An[q * 4 + 3] = -expf(v.w);
        }
    }
#pragma unroll
    for (int n = 0; n < SN; n++) h[n] = 0.f;

    float dsum = 0.f;
    size_t idx = row0 * SE + e;
    float d = delta[idx], uu = u[idx];
    for (int tl = 0; tl < ST; tl++) {
        float dn = 0.f, un = 0.f;
        if (tl + 1 < ST) { dn = delta[idx + SE]; un = u[idx + SE]; }
        const float du = d * uu;
        dsum += d;
#pragma unroll
        for (int n = 0; n < SN; n++) {
            const float dA = __expf(d * An[n]);
            h[n] = fmaf(dA, h[n], du * sB[tl * SN + n]);
        }
        d = dn; uu = un; idx += SE;
    }

    const size_t ob = ((((size_t)c * SB) + b) * SE + e) * SN;
#pragma unroll
    for (int q = 0; q < 4; q++) {
        float4 pv, sv;
        pv.x = __expf(An[q * 4 + 0] * dsum); sv.x = h[q * 4 + 0];
        pv.y = __expf(An[q * 4 + 1] * dsum); sv.y = h[q * 4 + 1];
        pv.z = __expf(An[q * 4 + 2] * dsum); sv.z = h[q * 4 + 2];
        pv.w = __expf(An[q * 4 + 3] * dsum); sv.w = h[q * 4 + 3];
        *(float4*)(Pbuf + ob + q * 4) = pv;
        *(float4*)(Sbuf + ob + q * 4) = sv;
    }
}

__global__ __launch_bounds__(256) void scan_pass2(
    const float* __restrict__ Pbuf, const float* __restrict__ Sbuf,
    float* __restrict__ hinit)
{
    const size_t g = (size_t)blockIdx.x * 256 + threadIdx.x;
    const size_t stride = (size_t)SB * SE * SN;
    float h = 0.f;
    float P = Pbuf[g], S = Sbuf[g];
    for (int c = 0; c < SC; c++) {
        float Pn = 0.f, Sn = 0.f;
        if (c + 1 < SC) {
            Pn = Pbuf[(c + 1) * stride + g];
            Sn = Sbuf[(c + 1) * stride + g];
        }
        hinit[c * stride + g] = h;
        h = fmaf(P, h, S);
        P = Pn; S = Sn;
    }
}

__global__ __launch_bounds__(256) void scan_pass3(
    const float* __restrict__ delta, const float* __restrict__ u,
    const float* __restrict__ proj, const float* __restrict__ A_log,
    const float* __restrict__ Dp, const float* __restrict__ xr,
    const float* __restrict__ hinit, ushort* __restrict__ yg)
{
    __shared__ float sB[ST * SN];
    __shared__ float sC[ST * SN];
    const int tid = threadIdx.x;
    const int eb = blockIdx.x & 7;
    const int c  = (blockIdx.x >> 3) & (SC - 1);
    const int b  = blockIdx.x >> 9;
    const int e  = eb * 256 + tid;
    const size_t row0 = (size_t)b * SL + c * ST;

    for (int i = tid; i < ST * SN; i += 256) {
        const int tl = i >> 4, n = i & 15;
        sB[i] = proj[(row0 + tl) * 160 + 128 + n];
        sC[i] = proj[(row0 + tl) * 160 + 144 + n];
    }
    __syncthreads();

    float An[SN], h[SN];
    {
        const float4* Ap = (const float4*)(A_log + (size_t)e * SN);
#pragma unroll
        for (int q = 0; q < 4; q++) {
            float4 v = Ap[q];
            An[q * 4 + 0] = -expf(v.x);
            An[q * 4 + 1] = -expf(v.y);
            An[q * 4 + 2] = -expf(v.z);
            An[q * 4 + 3] = -expf(v.w);
        }
    }
    {
        const size_t ib = ((((size_t)c * SB) + b) * SE + e) * SN;
#pragma unroll
        for (int q = 0; q < 4; q++) {
            float4 v = *(const float4*)(hinit + ib + q * 4);
            h[q * 4 + 0] = v.x; h[q * 4 + 1] = v.y;
            h[q * 4 + 2] = v.z; h[q * 4 + 3] = v.w;
        }
    }
    const float De = Dp[e];

    size_t idx = row0 * SE + e;
    float d = delta[idx], uu = u[idx], g = xr[idx];
    for (int tl = 0; tl < ST; tl++) {
        float dn = 0.f, un = 0.f, gn = 0.f;
        if (tl + 1 < ST) {
            dn = delta[idx + SE]; un = u[idx + SE]; gn = xr[idx + SE];
        }
        const float du = d * uu;
        float y = 0.f;
#pragma unroll
        for (int n = 0; n < SN; n++) {
            const float dA = __expf(d * An[n]);
            h[n] = fmaf(dA, h[n], du * sB[tl * SN + n]);
            y = fmaf(h[n], sC[tl * SN + n], y);
        }
        yg[idx] = f2bf((y + uu * De) * g);
        d = dn; uu = un; g = gn; idx += SE;
    }
}

extern "C" void kernel_launch(void* const* d_in, const int* in_sizes, int n_in,
                              void* d_out, int out_size, void* d_ws, size_t ws_size,
                              hipStream_t stream)
{
    const int Bc = 2, Lc = 2048, Hc = 1024, Ec = 2048;
    const int M = Bc * Lc;      // 4096
    const int PN = 160;
    const int SKZ = 8;          // GEMM3 split-K
    const int SK6 = 2;          // GEMM6 split-K

    const float* x        = (const float*)d_in[0];
    const float* W_in     = (const float*)d_in[1];
    const float* b_in     = (const float*)d_in[2];
    const float* conv_w   = (const float*)d_in[3];
    const float* conv_b   = (const float*)d_in[4];
    const float* x_proj_w = (const float*)d_in[5];
    const float* dt_proj_w= (const float*)d_in[6];
    const float* dt_bias  = (const float*)d_in[7];
    const float* A_log    = (const float*)d_in[8];
    const float* D_param  = (const float*)d_in[9];
    const float* W_out    = (const float*)d_in[10];
    const float* b_out    = (const float*)d_in[11];
    float* out = (float*)d_out;

    float* ws = (float*)d_ws;
    const size_t ME = (size_t)M * Ec;            // 8,388,608 floats
    const size_t PS = (size_t)SB * SE * SC * SN; // 4,194,304 floats

    // region map (floats):
    float* xc_raw = ws;                  // R0: GEMM1 out / Pp3 / P,S / ygbf
    float* xr     = xc_raw + ME;         // R1: xr, later Pp6
    float* xc     = xr + ME;             // R2: W_in_t early, then conv fp32 out
    float* delta  = xc + ME;             // R3: xbf, xc_bf, delta, then W_out_t
    float* proj   = delta + ME;
    float* hinit  = proj + (size_t)M * PN;  // also hosts xpw_t/dtw_t/dtbf pre-pass2

    ushort* xbf    = (ushort*)delta;
    ushort* W_in_t = (ushort*)xc;
    ushort* xc_bf  = (ushort*)delta;
    float*  Pp3    = xc_raw;                 // SKZ*M*160 = 5.24M floats
    ushort* xpw_t  = (ushort*)hinit;
    ushort* dtw_t  = (ushort*)hinit + 327680;
    ushort* dtbf   = (ushort*)hinit + 327680 + 262144;
    float*  Pbuf   = xc_raw;
    float*  Sbuf   = xc_raw + PS;
    ushort* ygbf   = (ushort*)xc_raw;
    ushort* W_out_t= (ushort*)delta;
    float*  Pp6    = xr;                     // SK6*M*1024 = 8.39M floats

    // 0) dtype conversions / weight transposes
    f2bf_vec<<<1024, 256, 0, stream>>>(x, xbf, (size_t)M * Hc / 4);
    f2bf_transpose<<<dim3(2 * Ec / 32, Hc / 32), 256, 0, stream>>>(
        W_in, W_in_t, Hc, 2 * Ec);
    f2bf_transpose<<<dim3(PN / 32, Ec / 32), 256, 0, stream>>>(
        x_proj_w, xpw_t, Ec, PN);
    f2bf_transpose<<<dim3(Ec / 32, 128 / 32), 256, 0, stream>>>(
        dt_proj_w, dtw_t, 128, Ec);

    // 1) z = x @ W_in + b_in ; split -> xc_raw (fp32), silu -> xr (fp32)
    g1_gemm<<<dim3(2 * Ec / 128, M / 128, 1), 256, 0, stream>>>(
        xbf, W_in_t, xc_raw, b_in, xr, M, 2 * Ec, Hc, Ec, Hc);

    // 2) depthwise causal conv + bias + silu -> xc (fp32) + xc_bf (bf16)
    conv_silu4<<<2048, 256, 0, stream>>>(
        xc_raw, conv_w, conv_b, xc, xc_bf, Lc, Ec, ME / 4);

    // 3) proj = xc @ x_proj_w : split-K bf16 MFMA + reduce (emits dt bf16 too)
    g3_gemm<<<dim3(2, M / 128, SKZ), 256, 0, stream>>>(
        xc_bf, xpw_t, Pp3, M, PN, Ec, Ec / SKZ);
    gemm3_reduce<<<(M * PN + 255) / 256, 256, 0, stream>>>(
        Pp3, proj, dtbf, M, PN, SKZ);

    // 4) delta = softplus(dt @ dt_proj_w + dt_bias) : K=128, high-occupancy
    g4_gemm<<<dim3(Ec / 128, M / 128), 256, 0, stream>>>(
        dtbf, dtw_t, delta, dt_bias, M, Ec);

    // 5) chunked parallel scan; pass3 emits bf16 yg
    scan_pass1<<<SB * SC * (SE / 256), 256, 0, stream>>>(
        delta, xc, proj, A_log, Pbuf, Sbuf);
    scan_pass2<<<(SB * SE * SN) / 256, 256, 0, stream>>>(Pbuf, Sbuf, hinit);
    scan_pass3<<<SB * SC * (SE / 256), 256, 0, stream>>>(
        delta, xc, proj, A_log, D_param, xr, hinit, ygbf);

    // 5b) W_out (E x H) -> bf16 (H x E)   (delta region dead now)
    f2bf_transpose<<<dim3(Hc / 32, Ec / 32), 256, 0, stream>>>(
        W_out, W_out_t, Ec, Hc);

    // 6) out = yg @ W_out : split-K=2 partials + bias reduce
    g6_gemm<<<dim3(Hc / 128, M / 128, SK6), 256, 0, stream>>>(
        ygbf, W_out_t, Pp6, M, Hc, Ec, Ec / SK6);
    reduce6<<<(int)((size_t)M * Hc / 4 + 255) / 256, 256, 0, stream>>>(
        Pp6, b_out, out, M, Hc, SK6);
}

// Round 10
// 311.959 us; speedup vs baseline: 1.4297x; 1.1568x over previous
//
#include <hip/hip_runtime.h>
#include <cstdint>

// scan geometry
#define SL 2048
#define SE 2048
#define SB 2
#define SN 16
#define SC 64
#define ST 32

enum { EP_SPLIT_SILU = 1, EP_PARTIAL = 4 };

typedef __attribute__((ext_vector_type(8))) short bf16x8;
typedef __attribute__((ext_vector_type(4))) float f32x4;

__device__ __forceinline__ float silu_f(float x) { return x / (1.f + __expf(-x)); }
__device__ __forceinline__ float softplus_f(float x) {
    return (x > 20.f) ? x : log1pf(__expf(x));
}
__device__ __forceinline__ ushort f2bf(float f) {
    union { float f; unsigned u; } a; a.f = f;
    unsigned r = a.u + 0x7fff + ((a.u >> 16) & 1);
    return (ushort)(r >> 16);
}
__device__ __forceinline__ float bf2f(ushort u) {
    union { float f; unsigned u; } a; a.u = ((unsigned)u) << 16;
    return a.f;
}
__device__ __forceinline__ void gload16(const void* g, void* l) {
    __builtin_amdgcn_global_load_lds(
        (const __attribute__((address_space(1))) unsigned int*)g,
        (__attribute__((address_space(3))) unsigned int*)l, 16, 0, 0);
}

// ---- shared 128x128 bf16 MFMA GEMM body, BK=64, dbuf LDS, 2-phase ----
template <int MODE>
__device__ __forceinline__ void gemm_body(
    const ushort* __restrict__ A, const ushort* __restrict__ Bt,
    float* __restrict__ C, const float* __restrict__ bias,
    float* __restrict__ out2, int M, int N, int K, int Esplit, int KS)
{
    __shared__ ushort As[2][128 * 64];
    __shared__ ushort Bs[2][128 * 64];
    const int tid = threadIdx.x;
    const int w = tid >> 6, l = tid & 63;
    const int wr = w >> 1, wc = w & 1;
    const int m0 = blockIdx.y * 128, n0 = blockIdx.x * 128;
    const int z = blockIdx.z;
    const int kbeg = z * KS;
    const int nt = KS / 64;
    const int srow = l >> 3, scol = (l & 7) * 8;

    f32x4 acc[4][4];
#pragma unroll
    for (int m = 0; m < 4; m++)
#pragma unroll
        for (int n = 0; n < 4; n++) acc[m][n] = (f32x4)(0.f);

    auto stage = [&](int buf, int t) {
        const int k0 = kbeg + t * 64;
#pragma unroll
        for (int r = 0; r < 4; r++) {
            const int row = r * 32 + w * 8 + srow;
            int brow = n0 + row; if (brow > N - 1) brow = N - 1;
            gload16(A + (size_t)(m0 + row) * K + k0 + scol,
                    &As[buf][r * 2048 + w * 512]);
            gload16(Bt + (size_t)brow * K + k0 + scol,
                    &Bs[buf][r * 2048 + w * 512]);
        }
    };

    stage(0, 0);
    __syncthreads();

    int cur = 0;
    const int fr = l & 15, kc = (l >> 4) * 8;
    for (int t = 0; t < nt; t++) {
        if (t + 1 < nt) stage(cur ^ 1, t + 1);
#pragma unroll
        for (int kk = 0; kk < 64; kk += 32) {
            bf16x8 af[4], bfr[4];
#pragma unroll
            for (int m = 0; m < 4; m++)
                af[m] = *(const bf16x8*)&As[cur][(wr * 64 + m * 16 + fr) * 64 + kk + kc];
#pragma unroll
            for (int n = 0; n < 4; n++)
                bfr[n] = *(const bf16x8*)&Bs[cur][(wc * 64 + n * 16 + fr) * 64 + kk + kc];
#pragma unroll
            for (int m = 0; m < 4; m++)
#pragma unroll
                for (int n = 0; n < 4; n++)
                    acc[m][n] = __builtin_amdgcn_mfma_f32_16x16x32_bf16(
                        af[m], bfr[n], acc[m][n], 0, 0, 0);
        }
        __syncthreads();
        cur ^= 1;
    }

    const int cr = (l >> 4) * 4, cc = l & 15;
    float* pbase = C + (size_t)z * M * N;
#pragma unroll
    for (int m = 0; m < 4; m++) {
#pragma unroll
        for (int j = 0; j < 4; j++) {
            const int row = m0 + wr * 64 + m * 16 + cr + j;
#pragma unroll
            for (int n = 0; n < 4; n++) {
                const int col = n0 + wc * 64 + n * 16 + cc;
                float v = acc[m][n][j];
                if (MODE == EP_SPLIT_SILU) {
                    v += bias[col];
                    if (col < Esplit)
                        C[(size_t)row * Esplit + col] = v;
                    else
                        out2[(size_t)row * Esplit + (col - Esplit)] = silu_f(v);
                } else {  // EP_PARTIAL
                    if (col < N) pbase[(size_t)row * N + col] = v;
                }
            }
        }
    }
}

__global__ __launch_bounds__(256, 2) void g1_gemm(
    const ushort* __restrict__ A, const ushort* __restrict__ Bt,
    float* __restrict__ C, const float* __restrict__ bias,
    float* __restrict__ out2, int M, int N, int K, int Esplit, int KS)
{ gemm_body<EP_SPLIT_SILU>(A, Bt, C, bias, out2, M, N, K, Esplit, KS); }

__global__ __launch_bounds__(256, 2) void g3_gemm(
    const ushort* __restrict__ A, const ushort* __restrict__ Bt,
    float* __restrict__ C, int M, int N, int K, int KS)
{ gemm_body<EP_PARTIAL>(A, Bt, C, nullptr, nullptr, M, N, K, 0, KS); }

__global__ __launch_bounds__(256, 2) void g6_gemm(
    const ushort* __restrict__ A, const ushort* __restrict__ Bt,
    float* __restrict__ C, int M, int N, int K, int KS)
{ gemm_body<EP_PARTIAL>(A, Bt, C, nullptr, nullptr, M, N, K, 0, KS); }

// ---- GEMM4: K=128, single-buffer; PURE GEMM epilogue -> bf16 raw (v + bias).
// Softplus moved to the scan consumers (isolates the epilogue hypothesis).
__global__ __launch_bounds__(256) void g4_gemm(
    const ushort* __restrict__ A, const ushort* __restrict__ Bt,
    ushort* __restrict__ draw, const float* __restrict__ bias, int M, int N)
{
    __shared__ ushort As[128 * 64];
    __shared__ ushort Bs[128 * 64];
    const int tid = threadIdx.x;
    const int w = tid >> 6, l = tid & 63;
    const int wr = w >> 1, wc = w & 1;
    const int m0 = blockIdx.y * 128, n0 = blockIdx.x * 128;
    const int srow = l >> 3, scol = (l & 7) * 8;
    const int K = 128;

    f32x4 acc[4][4];
#pragma unroll
    for (int m = 0; m < 4; m++)
#pragma unroll
        for (int n = 0; n < 4; n++) acc[m][n] = (f32x4)(0.f);

    const int fr = l & 15, kc = (l >> 4) * 8;
#pragma unroll
    for (int t = 0; t < 2; t++) {
        const int k0 = t * 64;
#pragma unroll
        for (int r = 0; r < 4; r++) {
            const int row = r * 32 + w * 8 + srow;
            gload16(A + (size_t)(m0 + row) * K + k0 + scol, &As[r * 2048 + w * 512]);
            gload16(Bt + (size_t)(n0 + row) * K + k0 + scol, &Bs[r * 2048 + w * 512]);
        }
        __syncthreads();
#pragma unroll
        for (int kk = 0; kk < 64; kk += 32) {
            bf16x8 af[4], bfr[4];
#pragma unroll
            for (int m = 0; m < 4; m++)
                af[m] = *(const bf16x8*)&As[(wr * 64 + m * 16 + fr) * 64 + kk + kc];
#pragma unroll
            for (int n = 0; n < 4; n++)
                bfr[n] = *(const bf16x8*)&Bs[(wc * 64 + n * 16 + fr) * 64 + kk + kc];
#pragma unroll
            for (int m = 0; m < 4; m++)
#pragma unroll
                for (int n = 0; n < 4; n++)
                    acc[m][n] = __builtin_amdgcn_mfma_f32_16x16x32_bf16(
                        af[m], bfr[n], acc[m][n], 0, 0, 0);
        }
        __syncthreads();
    }

    const int cr = (l >> 4) * 4, cc = l & 15;
#pragma unroll
    for (int m = 0; m < 4; m++) {
#pragma unroll
        for (int j = 0; j < 4; j++) {
            const int row = m0 + wr * 64 + m * 16 + cr + j;
#pragma unroll
            for (int n = 0; n < 4; n++) {
                const int col = n0 + wc * 64 + n * 16 + cc;
                draw[(size_t)row * N + col] = f2bf(acc[m][n][j] + bias[col]);
            }
        }
    }
}

// Reduce split-K partials -> proj fp32; also emit dt columns (<128) as bf16.
__global__ __launch_bounds__(256) void gemm3_reduce(
    const float* __restrict__ Pp, float* __restrict__ proj,
    ushort* __restrict__ dtbf, int M, int N, int Z)
{
    const size_t g = (size_t)blockIdx.x * 256 + threadIdx.x;
    const size_t tot = (size_t)M * N;
    if (g >= tot) return;
    float s = 0.f;
    for (int z = 0; z < Z; z++) s += Pp[(size_t)z * tot + g];
    proj[g] = s;
    const int col = (int)(g % N);
    if (col < 128) {
        const size_t row = g / N;
        dtbf[row * 128 + col] = f2bf(s);
    }
}

// Reduce GEMM6 split-K(Z) partials + bias -> out fp32 (float4).
__global__ __launch_bounds__(256) void reduce6(
    const float* __restrict__ Pp, const float* __restrict__ bias,
    float* __restrict__ out, int M, int N, int Z)
{
    const size_t g = (size_t)blockIdx.x * 256 + threadIdx.x;
    const size_t tot4 = (size_t)M * N / 4;
    if (g >= tot4) return;
    const int n4 = N / 4;
    float4 s = ((const float4*)bias)[g % n4];
    for (int z = 0; z < Z; z++) {
        float4 p = ((const float4*)Pp)[z * tot4 + g];
        s.x += p.x; s.y += p.y; s.z += p.z; s.w += p.w;
    }
    ((float4*)out)[g] = s;
}

// fp32 -> bf16 copy (vectorized)
__global__ __launch_bounds__(256) void f2bf_vec(
    const float* __restrict__ in, ushort* __restrict__ out, size_t n4)
{
    for (size_t i = (size_t)blockIdx.x * 256 + threadIdx.x; i < n4;
         i += (size_t)gridDim.x * 256) {
        float4 v = ((const float4*)in)[i];
        ushort4 o;
        o.x = f2bf(v.x); o.y = f2bf(v.y); o.z = f2bf(v.z); o.w = f2bf(v.w);
        ((ushort4*)out)[i] = o;
    }
}

// W (R x Ccols) fp32 -> Wt (Ccols x R) bf16, tiled transpose
__global__ __launch_bounds__(256) void f2bf_transpose(
    const float* __restrict__ W, ushort* __restrict__ Wt, int R, int Ccols)
{
    __shared__ float tile[32][33];
    const int bc = blockIdx.x * 32, br = blockIdx.y * 32;
    const int tx = threadIdx.x & 31, ty = threadIdx.x >> 5;
    for (int i = ty; i < 32; i += 8)
        tile[i][tx] = W[(size_t)(br + i) * Ccols + bc + tx];
    __syncthreads();
    for (int i = ty; i < 32; i += 8)
        Wt[(size_t)(bc + i) * R + br + tx] = f2bf(tile[tx][i]);
}

// Depthwise causal conv (K=4) + bias + SiLU; 4 ch/thread; bf16 output only.
__global__ __launch_bounds__(256) void conv_silu4(
    const float* __restrict__ xin, const float* __restrict__ w,
    const float* __restrict__ cb, ushort* __restrict__ xobf,
    int Ln, int En, size_t total4)
{
    const int Eq = En >> 2;
    for (size_t idx = (size_t)blockIdx.x * 256 + threadIdx.x; idx < total4;
         idx += (size_t)gridDim.x * 256) {
        const int e4 = (int)(idx % Eq);
        const size_t row = idx / Eq;
        const int l = (int)(row % Ln);
        float4 acc = ((const float4*)cb)[e4];
        const float4 w0 = ((const float4*)w)[e4 * 4 + 0];
        const float4 w1 = ((const float4*)w)[e4 * 4 + 1];
        const float4 w2 = ((const float4*)w)[e4 * 4 + 2];
        const float4 w3 = ((const float4*)w)[e4 * 4 + 3];
        const float wt0[4] = {w0.x, w0.y, w0.z, w0.w};
        const float wt1[4] = {w1.x, w1.y, w1.z, w1.w};
        const float wt2[4] = {w2.x, w2.y, w2.z, w2.w};
        const float wt3[4] = {w3.x, w3.y, w3.z, w3.w};
#pragma unroll
        for (int k = 0; k < 4; k++) {
            if (l - 3 + k >= 0) {
                float4 xv = ((const float4*)xin)[(row - 3 + k) * Eq + e4];
                acc.x = fmaf(wt0[k], xv.x, acc.x);
                acc.y = fmaf(wt1[k], xv.y, acc.y);
                acc.z = fmaf(wt2[k], xv.z, acc.z);
                acc.w = fmaf(wt3[k], xv.w, acc.w);
            }
        }
        ushort4 o;
        o.x = f2bf(silu_f(acc.x)); o.y = f2bf(silu_f(acc.y));
        o.z = f2bf(silu_f(acc.z)); o.w = f2bf(silu_f(acc.w));
        ((ushort4*)xobf)[idx] = o;
    }
}

// ---- Chunked parallel selective scan (delta raw bf16 + softplus here; u bf16) ----
__global__ __launch_bounds__(256) void scan_pass1(
    const ushort* __restrict__ draw, const ushort* __restrict__ u,
    const float* __restrict__ proj, const float* __restrict__ A_log,
    float* __restrict__ Pbuf, float* __restrict__ Sbuf)
{
    __shared__ float sB[ST * SN];
    const int tid = threadIdx.x;
    const int eb = blockIdx.x & 7;
    const int c  = (blockIdx.x >> 3) & (SC - 1);
    const int b  = blockIdx.x >> 9;
    const int e  = eb * 256 + tid;
    const size_t row0 = (size_t)b * SL + c * ST;

    for (int i = tid; i < ST * SN; i += 256) {
        const int tl = i >> 4, n = i & 15;
        sB[i] = proj[(row0 + tl) * 160 + 128 + n];
    }
    __syncthreads();

    float An[SN], h[SN];
    {
        const float4* Ap = (const float4*)(A_log + (size_t)e * SN);
#pragma unroll
        for (int q = 0; q < 4; q++) {
            float4 v = Ap[q];
            An[q * 4 + 0] = -expf(v.x);
            An[q * 4 + 1] = -expf(v.y);
            An[q * 4 + 2] = -expf(v.z);
            An[q * 4 + 3] = -expf(v.w);
        }
    }
#pragma unroll
    for (int n = 0; n < SN; n++) h[n] = 0.f;

    float dsum = 0.f;
    size_t idx = row0 * SE + e;
    float d = softplus_f(bf2f(draw[idx])), uu = bf2f(u[idx]);
    for (int tl = 0; tl < ST; tl++) {
        ushort dn = 0, un = 0;
        if (tl + 1 < ST) { dn = draw[idx + SE]; un = u[idx + SE]; }
        const float du = d * uu;
        dsum += d;
#pragma unroll
        for (int n = 0; n < SN; n++) {
            const float dA = __expf(d * An[n]);
            h[n] = fmaf(dA, h[n], du * sB[tl * SN + n]);
        }
        d = softplus_f(bf2f(dn)); uu = bf2f(un); idx += SE;
    }

    const size_t ob = ((((size_t)c * SB) + b) * SE + e) * SN;
#pragma unroll
    for (int q = 0; q < 4; q++) {
        float4 pv, sv;
        pv.x = __expf(An[q * 4 + 0] * dsum); sv.x = h[q * 4 + 0];
        pv.y = __expf(An[q * 4 + 1] * dsum); sv.y = h[q * 4 + 1];
        pv.z = __expf(An[q * 4 + 2] * dsum); sv.z = h[q * 4 + 2];
        pv.w = __expf(An[q * 4 + 3] * dsum); sv.w = h[q * 4 + 3];
        *(float4*)(Pbuf + ob + q * 4) = pv;
        *(float4*)(Sbuf + ob + q * 4) = sv;
    }
}

__global__ __launch_bounds__(256) void scan_pass2(
    const float* __restrict__ Pbuf, const float* __restrict__ Sbuf,
    float* __restrict__ hinit)
{
    const size_t g = (size_t)blockIdx.x * 256 + threadIdx.x;
    const size_t stride = (size_t)SB * SE * SN;
    float h = 0.f;
    float P = Pbuf[g], S = Sbuf[g];
    for (int c = 0; c < SC; c++) {
        float Pn = 0.f, Sn = 0.f;
        if (c + 1 < SC) {
            Pn = Pbuf[(c + 1) * stride + g];
            Sn = Sbuf[(c + 1) * stride + g];
        }
        hinit[c * stride + g] = h;
        h = fmaf(P, h, S);
        P = Pn; S = Sn;
    }
}

__global__ __launch_bounds__(256) void scan_pass3(
    const ushort* __restrict__ draw, const ushort* __restrict__ u,
    const float* __restrict__ proj, const float* __restrict__ A_log,
    const float* __restrict__ Dp, const float* __restrict__ xr,
    const float* __restrict__ hinit, ushort* __restrict__ yg)
{
    __shared__ float sB[ST * SN];
    __shared__ float sC[ST * SN];
    const int tid = threadIdx.x;
    const int eb = blockIdx.x & 7;
    const int c  = (blockIdx.x >> 3) & (SC - 1);
    const int b  = blockIdx.x >> 9;
    const int e  = eb * 256 + tid;
    const size_t row0 = (size_t)b * SL + c * ST;

    for (int i = tid; i < ST * SN; i += 256) {
        const int tl = i >> 4, n = i & 15;
        sB[i] = proj[(row0 + tl) * 160 + 128 + n];
        sC[i] = proj[(row0 + tl) * 160 + 144 + n];
    }
    __syncthreads();

    float An[SN], h[SN];
    {
        const float4* Ap = (const float4*)(A_log + (size_t)e * SN);
#pragma unroll
        for (int q = 0; q < 4; q++) {
            float4 v = Ap[q];
            An[q * 4 + 0] = -expf(v.x);
            An[q * 4 + 1] = -expf(v.y);
            An[q * 4 + 2] = -expf(v.z);
            An[q * 4 + 3] = -expf(v.w);
        }
    }
    {
        const size_t ib = ((((size_t)c * SB) + b) * SE + e) * SN;
#pragma unroll
        for (int q = 0; q < 4; q++) {
            float4 v = *(const float4*)(hinit + ib + q * 4);
            h[q * 4 + 0] = v.x; h[q * 4 + 1] = v.y;
            h[q * 4 + 2] = v.z; h[q * 4 + 3] = v.w;
        }
    }
    const float De = Dp[e];

    size_t idx = row0 * SE + e;
    float d = softplus_f(bf2f(draw[idx])), uu = bf2f(u[idx]), g = xr[idx];
    for (int tl = 0; tl < ST; tl++) {
        ushort dn = 0, un = 0;
        float gn = 0.f;
        if (tl + 1 < ST) {
            dn = draw[idx + SE]; un = u[idx + SE]; gn = xr[idx + SE];
        }
        const float du = d * uu;
        float y = 0.f;
#pragma unroll
        for (int n = 0; n < SN; n++) {
            const float dA = __expf(d * An[n]);
            h[n] = fmaf(dA, h[n], du * sB[tl * SN + n]);
            y = fmaf(h[n], sC[tl * SN + n], y);
        }
        yg[idx] = f2bf((y + uu * De) * g);
        d = softplus_f(bf2f(dn)); uu = bf2f(un); g = gn; idx += SE;
    }
}

extern "C" void kernel_launch(void* const* d_in, const int* in_sizes, int n_in,
                              void* d_out, int out_size, void* d_ws, size_t ws_size,
                              hipStream_t stream)
{
    const int Bc = 2, Lc = 2048, Hc = 1024, Ec = 2048;
    const int M = Bc * Lc;      // 4096
    const int PN = 160;
    const int SKZ = 8;          // GEMM3 split-K
    const int SK6 = 2;          // GEMM6 split-K

    const float* x        = (const float*)d_in[0];
    const float* W_in     = (const float*)d_in[1];
    const float* b_in     = (const float*)d_in[2];
    const float* conv_w   = (const float*)d_in[3];
    const float* conv_b   = (const float*)d_in[4];
    const float* x_proj_w = (const float*)d_in[5];
    const float* dt_proj_w= (const float*)d_in[6];
    const float* dt_bias  = (const float*)d_in[7];
    const float* A_log    = (const float*)d_in[8];
    const float* D_param  = (const float*)d_in[9];
    const float* W_out    = (const float*)d_in[10];
    const float* b_out    = (const float*)d_in[11];
    float* out = (float*)d_out;

    float* ws = (float*)d_ws;
    const size_t ME = (size_t)M * Ec;            // 8,388,608 floats
    const size_t PS = (size_t)SB * SE * SC * SN; // 4,194,304 floats

    // region map (floats):
    float* xc_raw = ws;                  // R0: GEMM1 z-out (conv input) / Pp3 / P,S / ygbf
    float* xr     = xc_raw + ME;         // R1: xr gate -> Pp6 after pass3
    float* r2     = xr + ME;             // R2: W_in_t early -> xc_bf (conv out)
    float* r3     = r2 + ME;             // R3: xbf early -> draw (bf16) -> W_out_t
    float* proj   = r3 + ME;
    float* hinit  = proj + (size_t)M * PN;  // also hosts xpw_t/dtw_t/dtbf pre-pass2

    ushort* xbf    = (ushort*)r3;            // dead after g1
    ushort* W_in_t = (ushort*)r2;            // dead after g1
    ushort* xc_bf  = (ushort*)r2;            // conv bf16 out; u for g3+scans
    ushort* draw   = (ushort*)r3;            // g4 raw bf16 out (16.7MB)
    float*  Pp3    = xc_raw;                 // SKZ*M*160 = 5.24M floats
    ushort* xpw_t  = (ushort*)hinit;
    ushort* dtw_t  = (ushort*)hinit + 327680;
    ushort* dtbf   = (ushort*)hinit + 327680 + 262144;
    float*  Pbuf   = xc_raw;
    float*  Sbuf   = xc_raw + PS;
    ushort* ygbf   = (ushort*)xc_raw;
    ushort* W_out_t= (ushort*)r3;            // after pass3 (draw dead)
    float*  Pp6    = xr;                     // SK6*M*1024 (xr dead after pass3)

    // 0) dtype conversions / weight transposes
    f2bf_vec<<<1024, 256, 0, stream>>>(x, xbf, (size_t)M * Hc / 4);
    f2bf_transpose<<<dim3(2 * Ec / 32, Hc / 32), 256, 0, stream>>>(
        W_in, W_in_t, Hc, 2 * Ec);
    f2bf_transpose<<<dim3(PN / 32, Ec / 32), 256, 0, stream>>>(
        x_proj_w, xpw_t, Ec, PN);
    f2bf_transpose<<<dim3(Ec / 32, 128 / 32), 256, 0, stream>>>(
        dt_proj_w, dtw_t, 128, Ec);

    // 1) z = x @ W_in + b_in ; split -> xc_raw (fp32), silu -> xr (fp32)
    g1_gemm<<<dim3(2 * Ec / 128, M / 128, 1), 256, 0, stream>>>(
        xbf, W_in_t, xc_raw, b_in, xr, M, 2 * Ec, Hc, Ec, Hc);

    // 2) depthwise causal conv + bias + silu -> xc_bf (bf16 only)
    conv_silu4<<<2048, 256, 0, stream>>>(
        xc_raw, conv_w, conv_b, xc_bf, Lc, Ec, ME / 4);

    // 3) proj = xc @ x_proj_w : split-K bf16 MFMA + reduce (emits dt bf16 too)
    g3_gemm<<<dim3(2, M / 128, SKZ), 256, 0, stream>>>(
        xc_bf, xpw_t, Pp3, M, PN, Ec, Ec / SKZ);
    gemm3_reduce<<<(M * PN + 255) / 256, 256, 0, stream>>>(
        Pp3, proj, dtbf, M, PN, SKZ);

    // 4) draw = dt @ dt_proj_w + dt_bias (bf16 raw; softplus in scans)
    g4_gemm<<<dim3(Ec / 128, M / 128), 256, 0, stream>>>(
        dtbf, dtw_t, draw, dt_bias, M, Ec);

    // 5) chunked parallel scan; pass3 emits bf16 yg
    scan_pass1<<<SB * SC * (SE / 256), 256, 0, stream>>>(
        draw, xc_bf, proj, A_log, Pbuf, Sbuf);
    scan_pass2<<<(SB * SE * SN) / 256, 256, 0, stream>>>(Pbuf, Sbuf, hinit);
    scan_pass3<<<SB * SC * (SE / 256), 256, 0, stream>>>(
        draw, xc_bf, proj, A_log, D_param, xr, hinit, ygbf);

    // 5b) W_out (E x H) -> bf16 (H x E)  (draw dead now)
    f2bf_transpose<<<dim3(Hc / 32, Ec / 32), 256, 0, stream>>>(
        W_out, W_out_t, Ec, Hc);

    // 6) out = yg @ W_out : split-K=2 partials + bias reduce
    g6_gemm<<<dim3(Hc / 128, M / 128, SK6), 256, 0, stream>>>(
        ygbf, W_out_t, Pp6, M, Hc, Ec, Ec / SK6);
    reduce6<<<(int)((size_t)M * Hc / 4 + 255) / 256, 256, 0, stream>>>(
        Pp6, b_out, out, M, Hc, SK6);
}